// Round 17
// baseline (227.664 us; speedup 1.0000x reference)
//
#include <hip/hip_runtime.h>
#include <math.h>

// Problem constants (fixed by reference)
#define NN   10000
#define EE   160000
#define GG   128
#define HIDK 25
#define KROWS 32     // 25 MLP rows + 1 b2 row + 1 wr row (26) + 1 bc row (27) + 4 pad
#define KB   28      // Phase-B row count (rows 0..27 are real)
#define DOUT 32
#define EPSBN 1e-5f
#define PREPB 1024   // k_prep grid: 262144 threads -> 1 edge/thread, 4 waves/SIMD
#define WPACKN (KROWS * 16 * DOUT + KROWS * 32 * DOUT)   // 49152
#define MAXD 48      // padded bucket slots/node; Poisson(16): P(>48)~1e-12 -> safe

// ---------------- workspace layout (float offsets) ----------------
// zeroed region (one hipMemsetAsync):
#define OFF_CUR   0          // NN ints (bucket cursors == final degrees), pad 10016
#define OFF_GSUM  10016      // G*32 = 4096
#define OFF_GCNT  14112      // GG ints, pad 128
#define OFF_BINC  14240      // MAXD+1 bin cursors (ints), pad 64
#define ZERO_FLOATS 14304
// non-zeroed:
#define OFF_MOP   14304      // PREPB*12 per-block moment partials (plain stores)
#define OFF_W1F0  26592      // 80
#define OFF_B1F0  26672      // 32
#define OFF_W1F1  26704      // 80
#define OFF_B1F1  26784      // 32
#define OFF_BOFF  26816      // MAXD+1 bin offsets (ints), pad 64
#define OFF_PERM  26880      // NN ints (degree-sorted node order), pad 10016
#define OFF_EA    36896      // NN*MAXD*4 floats: {a0,a1,a2,src-bits} in bucket order
#define OFF_WB0   1956896    // 32*16*32 = 16384
#define OFF_WB1   1973280    // 32*32*32 = 32768
#define OFF_X1    2006048    // N*32
#define TOTAL_FLOATS 2326048 // ~9.3 MB of d_ws

// ============================================================================
// SESSION LEDGER (R17 = R16 resubmit; R16 was an infra failure, not a kernel
// verdict -- same as R1). Base = R12 (~196 us; band 193.7-197.6 over 3 runs).
//  * k_fused: MINW=6 + shallow (1-iter) prefetch ONLY. Any added per-wave
//    state spills: MINW=7/8 (R3/R6/R13), 3-deep pipeline (R14) -> WRITE_SIZE
//    29-185 MB. hipcc allocator sits at the budget edge.
//  * Phase-B remap abandoned (R10 conflicts / R11 codegen regression).
//  * Grid tickets only at O(100) blocks (R5/R7/R8). Same-line atomics across
//    1000+ blocks serialize (R9) -> per-block partials + reduce kernel.
//  * R16 NEW: degree-sorted node order (counting sort, 49 bins) to kill
//    intra-block max-of-4 imbalance (E[max4 Poisson16] ~ 20 vs mean 16).
// ============================================================================

__device__ inline float wave_red(float v) {
    for (int off = 32; off; off >>= 1) v += __shfl_down(v, off);
    return v;
}

// ---- pack wbig[k][i4][o][c] = W[k][i4*4+c][o]   (R9-proven layout)
// rows 0..24 = w2; 25 = b2; 26 = wr (root fold); 27 = bc (bias, i==0); rest 0
template <int DIN>
__device__ inline void wpack(int idx, const float* __restrict__ w2,
                             const float* __restrict__ b2,
                             const float* __restrict__ wr,
                             const float* __restrict__ bc,
                             float* __restrict__ wbig) {
    int k = idx / (DIN * DOUT);
    int rem = idx - k * (DIN * DOUT);
    int i4 = rem / (4 * DOUT);
    int rem2 = rem - i4 * (4 * DOUT);
    int o = rem2 >> 2, c = rem2 & 3;
    int i = i4 * 4 + c;
    float v = 0.f;
    if (k < HIDK) v = w2[(k * DIN + i) * DOUT + o];
    else if (k == HIDK) v = b2[i * DOUT + o];
    else if (k == HIDK + 1) v = wr[i * DOUT + o];
    else if (k == HIDK + 2) v = (i == 0) ? bc[o] : 0.f;
    wbig[idx] = v;
}

// ---- prep kernel, 1024 blocks, one edge/thread. NO grid ticket (R8: convoy),
// NO same-line gmom atomics (R9): moments -> per-block partials (plain stores).
__global__ void k_prep(const float* __restrict__ ea, const int* __restrict__ ei,
                       const int* __restrict__ batch,
                       const float* __restrict__ w2_0, const float* __restrict__ b2_0,
                       const float* __restrict__ wr_0, const float* __restrict__ bc_0,
                       const float* __restrict__ w2_1, const float* __restrict__ b2_1,
                       const float* __restrict__ wr_1, const float* __restrict__ bc_1,
                       float* __restrict__ mop, int* __restrict__ cur,
                       int* __restrict__ gcnt, float* __restrict__ eab,
                       float* __restrict__ wb0, float* __restrict__ wb1) {
    __shared__ float ls[4][9];
    int t = threadIdx.x;
    int idx = blockIdx.x * 256 + t;

    // -- weight pack (guarded; independent)
    if (idx < KROWS * 16 * DOUT) wpack<16>(idx, w2_0, b2_0, wr_0, bc_0, wb0);
    else if (idx < WPACKN) wpack<32>(idx - KROWS * 16 * DOUT, w2_1, b2_1, wr_1, bc_1, wb1);

    // -- one edge per thread: moments + bucket scatter (single 16B write;
    //    src index embedded in .w as int bits -> no separate bsrc array)
    float s[9];
#pragma unroll
    for (int j = 0; j < 9; j++) s[j] = 0.f;
    if (idx < EE) {
        float a0 = ea[3 * idx], a1 = ea[3 * idx + 1], a2 = ea[3 * idx + 2];
        s[0] = a0; s[1] = a1; s[2] = a2;
        s[3] = a0 * a0; s[4] = a0 * a1; s[5] = a0 * a2;
        s[6] = a1 * a1; s[7] = a1 * a2; s[8] = a2 * a2;
        int d = ei[EE + idx];
        int pos = atomicAdd(cur + d, 1);
        if (pos < MAXD) {                       // deterministically never exceeded
            int slot = d * MAXD + pos;
            float4 av = { a0, a1, a2, __int_as_float(ei[idx]) };
            *(float4*)(eab + 4 * (size_t)slot) = av;
        }
    }
    // -- nodes-per-graph counts (128 counters, ~80 RMW/line -> fine)
    if (idx < NN) atomicAdd(gcnt + batch[idx], 1);

    int w = t >> 6, lane = t & 63;
#pragma unroll
    for (int j = 0; j < 9; j++) {
        float r = wave_red(s[j]);
        if (lane == 0) ls[w][j] = r;
    }
    __syncthreads();
    if (t < 9) mop[blockIdx.x * 12 + t] = ls[0][t] + ls[1][t] + ls[2][t] + ls[3][t];
}

// ---- reduce moment partials + BN fold + degree histogram/prefix,
// 1 block x 256 threads (stream order replaces any device ticket)
__global__ void k_fold(const float* __restrict__ mop,
                       const int* __restrict__ cur,
                       const float* __restrict__ w1_0, const float* __restrict__ b1_0,
                       const float* __restrict__ g_0, const float* __restrict__ be_0,
                       const float* __restrict__ w1_1, const float* __restrict__ b1_1,
                       const float* __restrict__ g_1, const float* __restrict__ be_1,
                       float* __restrict__ w1f0, float* __restrict__ b1f0,
                       float* __restrict__ w1f1, float* __restrict__ b1f1,
                       int* __restrict__ binoff) {
    __shared__ float ls[4][9];
    __shared__ float mo[9];
    __shared__ int hist[MAXD + 1];
    int t = threadIdx.x;
    if (t <= MAXD) hist[t] = 0;
    float s[9];
#pragma unroll
    for (int j = 0; j < 9; j++) s[j] = 0.f;
    for (int b = t; b < PREPB; b += 256) {
#pragma unroll
        for (int j = 0; j < 9; j++) s[j] += mop[b * 12 + j];
    }
    int w = t >> 6, lane = t & 63;
#pragma unroll
    for (int j = 0; j < 9; j++) {
        float r = wave_red(s[j]);
        if (lane == 0) ls[w][j] = r;
    }
    __syncthreads();
    if (t < 9) mo[t] = ls[0][t] + ls[1][t] + ls[2][t] + ls[3][t];
    // degree histogram (LDS atomics; 49 bins)
    for (int nn = t; nn < NN; nn += 256) {
        int d = cur[nn]; if (d > MAXD) d = MAXD;
        atomicAdd(&hist[d], 1);
    }
    __syncthreads();
    if (t == 0) {
        int run = 0;
        for (int d = 0; d <= MAXD; d++) { binoff[d] = run; run += hist[d]; }
    }
    if (t < 64) {
        int grp = t >> 5, j = t & 31;
        if (j < HIDK) {
            const float* w1 = grp ? w1_1 : w1_0;
            const float* b1 = grp ? b1_1 : b1_0;
            const float* g  = grp ? g_1  : g_0;
            const float* be = grp ? be_1 : be_0;
            float* w1f = grp ? w1f1 : w1f0;
            float* b1f = grp ? b1f1 : b1f0;
            const float inv = 1.0f / (float)EE;
            float m0 = mo[0] * inv, m1 = mo[1] * inv, m2 = mo[2] * inv;
            float c00 = mo[3] * inv - m0 * m0, c01 = mo[4] * inv - m0 * m1;
            float c02 = mo[5] * inv - m0 * m2, c11 = mo[6] * inv - m1 * m1;
            float c12 = mo[7] * inv - m1 * m2, c22 = mo[8] * inv - m2 * m2;
            float w0 = w1[j], wa = w1[25 + j], wb = w1[50 + j];
            float mean = m0 * w0 + m1 * wa + m2 * wb + b1[j];
            float var = w0 * w0 * c00 + wa * wa * c11 + wb * wb * c22
                      + 2.f * (w0 * wa * c01 + w0 * wb * c02 + wa * wb * c12);
            float sc = g[j] * rsqrtf(var + EPSBN);
            w1f[j] = w0 * sc; w1f[25 + j] = wa * sc; w1f[50 + j] = wb * sc;
            b1f[j] = (b1[j] - mean) * sc + be[j];
        }
    }
}

// ---- build degree-sorted permutation: perm[binoff[d] + rank] = node.
// 40 blocks; 10K atomics over 49 counters (L2-resident, parallel bins).
__global__ void k_perm(const int* __restrict__ cur, const int* __restrict__ binoff,
                       int* __restrict__ binc, int* __restrict__ perm) {
    int nn = blockIdx.x * 256 + threadIdx.x;
    if (nn >= NN) return;
    int d = cur[nn]; if (d > MAXD) d = MAXD;
    int pos = atomicAdd(binc + d, 1);
    perm[binoff[d] + pos] = nn;
}

// ---- FUSED layer kernel (R12 schedule + degree-sorted node order). ONE wave
// per node, 4 nodes/block; node = perm[blockIdx*4+w] so a block's 4 nodes have
// near-equal degree (kills the max-of-4 Phase-A imbalance). MINW=6 + shallow
// prefetch ONLY -- see ledger. Tripwire: WRITE_SIZE > 5MB => spill => revert.
// Phase A: single load stream -- src rides in eab.w, extracted via 2 broadcast
// shuffles; h lane-parallel, double-buffered through LDS (intra-wave).
// Phase B (R9 v1): wave w covers k-rows [7w,7w+7) for ALL 4 nodes, half-waves
// split the i4 range; W read once per block.
// FINAL=true: epilogue atomicAdds into gsum ONLY (no grid ticket -- R5).
template <int DIN, int KPL, bool FINAL>
__global__ __launch_bounds__(256, 6)
void k_fused(const int* __restrict__ cnt,
             const int* __restrict__ perm,
             const float* __restrict__ eab,
             const float* __restrict__ w1f, const float* __restrict__ b1f,
             const float* __restrict__ wbig, const float* __restrict__ xin,
             const int* __restrict__ batch,
             float* __restrict__ xout, float* __restrict__ gsum) {
    __shared__ __align__(16) float Slds[4][KROWS][DIN];
    __shared__ float Olds[4][4][DOUT];                 // [wave][node][o]
    __shared__ __align__(16) float hb[4][2][2][32];    // [wave][buf][half][k]
    int t = threadIdx.x;
    int w = t >> 6, lane = t & 63;
    int n = perm[blockIdx.x * 4 + w];      // degree-sorted order
    int dg = cnt[n];
    int start = n * MAXD;
    int end = start + (dg > MAXD ? MAXD : dg);

    int il = lane & (DIN - 1);
    int kh = lane / DIN;                   // 64/DIN k-groups
    int kme = lane & 31;                   // which h-row this lane computes
    int half = lane >> 5;                  // 0: edge A (p), 1: edge B (p+1)

    // per-lane folded edge-MLP coefficients (loop-invariant)
    float c0 = 0.f, c1 = 0.f, c2 = 0.f, c3 = 0.f;
    if (kme < HIDK) {
        c0 = w1f[kme]; c1 = w1f[25 + kme]; c2 = w1f[50 + kme]; c3 = b1f[kme];
    } else if (kme == HIDK) {
        c3 = 1.0f;                         // b2 row: relu(1) == 1
    }

    float x_own = xin[n * DIN + il];       // own-node feature (root-fold row 26)

    float s[KPL];
#pragma unroll
    for (int j = 0; j < KPL; j++) s[j] = 0.f;

    const float4* ea4 = (const float4*)eab;

    // ---- Phase A (software-pipelined, 2 edges/iter) ----
    int p = start;
    int vB0 = 0, vB1 = 0;
    float xA = 0.f, xB = 0.f;              // x values for pair p
    float4 av1 = {0.f, 0.f, 0.f, 0.f};     // attrs+src for pair p+2 (this half)
    int buf = 0;

    if (p < end) {
        vB0 = (p + 1 < end); int qB0 = vB0 ? p + 1 : p;
        float4 av0 = ea4[half ? qB0 : p];
        int p1 = p + 2;
        if (p1 < end) {
            vB1 = (p1 + 1 < end); int qB1 = vB1 ? p1 + 1 : p1;
            av1 = ea4[half ? qB1 : p1];
        }
        int me0 = __float_as_int(av0.w);
        int sA0 = __shfl(me0, 0), sB0 = __shfl(me0, 32);
        xA = xin[sA0 * DIN + il];
        xB = xin[sB0 * DIN + il];
        float hv = av0.x * c0 + av0.y * c1 + av0.z * c2 + c3;
        hv = hv > 0.f ? hv : 0.f;
        hb[w][0][half][kme] = hv;
    }
    while (p < end) {
        int p1 = p + 2, p2 = p + 4;
        // prefetch next-next pair's attrs+src (address-only dependency)
        float4 av2 = {0.f, 0.f, 0.f, 0.f};
        int vB2 = 0;
        if (p2 < end) {
            vB2 = (p2 + 1 < end); int qB2 = vB2 ? p2 + 1 : p2;
            av2 = ea4[half ? qB2 : p2];
        }
        // extract next pair's srcs from av1 (arrived) and prefetch x
        int me1 = __float_as_int(av1.w);
        int sA1 = __shfl(me1, 0), sB1 = __shfl(me1, 32);
        float xAn = 0.f, xBn = 0.f;
        if (p1 < end) { xAn = xin[sA1 * DIN + il]; xBn = xin[sB1 * DIN + il]; }
        // read current h BEFORE this iter's write (in-order DS queue, same wave)
        const float4* hA4 = (const float4*)&hb[w][buf][0][kh * KPL];
        const float4* hB4 = (const float4*)&hb[w][buf][1][kh * KPL];
        float4 ha[KPL / 4], hc[KPL / 4];
#pragma unroll
        for (int j4 = 0; j4 < KPL / 4; j4++) { ha[j4] = hA4[j4]; hc[j4] = hB4[j4]; }
        // write next pair's h (av1 arrived)
        if (p1 < end) {
            float hv = av1.x * c0 + av1.y * c1 + av1.z * c2 + c3;
            hv = hv > 0.f ? hv : 0.f;
            hb[w][buf ^ 1][half][kme] = hv;
        }
        float xBm = vB0 ? xB : 0.f;
#pragma unroll
        for (int j4 = 0; j4 < KPL / 4; j4++) {
            s[j4 * 4 + 0] += ha[j4].x * xA; s[j4 * 4 + 1] += ha[j4].y * xA;
            s[j4 * 4 + 2] += ha[j4].z * xA; s[j4 * 4 + 3] += ha[j4].w * xA;
        }
#pragma unroll
        for (int j4 = 0; j4 < KPL / 4; j4++) {
            s[j4 * 4 + 0] += hc[j4].x * xBm; s[j4 * 4 + 1] += hc[j4].y * xBm;
            s[j4 * 4 + 2] += hc[j4].z * xBm; s[j4 * 4 + 3] += hc[j4].w * xBm;
        }
        p = p1;
        vB0 = vB1; vB1 = vB2;
        xA = xAn; xB = xBn; av1 = av2;
        buf ^= 1;
    }
#pragma unroll
    for (int j = 0; j < KPL; j++)
        Slds[w][kh * KPL + j][il] = s[j];
    // fold rows: 26 = d*x_own (root), 27 = d at i==0 (bias). Same-wave later
    // writes override the zeros Phase A stored there (LDS ops in program order).
    float dmul = (float)dg; if (dmul < 1.f) dmul = 1.f;
    if (half == 0) {
        Slds[w][26][il] = dmul * x_own;
        Slds[w][27][il] = (il == 0) ? dmul : 0.f;
    }
    __syncthreads();

    // ---- Phase B (R9): wave w covers k-rows [7w, 7w+7) for all 4 nodes;
    //      half-waves split the i4 range; each W float4 read once per block.
    {
        int o = lane & 31, hf = lane >> 5;
        constexpr int I4H = DIN / 8;        // i4 per half-wave
        const float4* wb4 = (const float4*)wbig;
        float a0 = 0.f, a1 = 0.f, a2 = 0.f, a3 = 0.f;
        int kbase = w * (KB / 4);
#pragma unroll
        for (int kk = 0; kk < KB / 4; kk++) {
            int k = kbase + kk;
#pragma unroll
            for (int j = 0; j < I4H; j++) {
                int i4 = hf * I4H + j;
                float4 wv = wb4[(k * (DIN / 4) + i4) * 32 + o];
                float4 s0 = *(const float4*)&Slds[0][k][i4 * 4];
                float4 s1 = *(const float4*)&Slds[1][k][i4 * 4];
                float4 s2 = *(const float4*)&Slds[2][k][i4 * 4];
                float4 s3 = *(const float4*)&Slds[3][k][i4 * 4];
                a0 += s0.x * wv.x + s0.y * wv.y + s0.z * wv.z + s0.w * wv.w;
                a1 += s1.x * wv.x + s1.y * wv.y + s1.z * wv.z + s1.w * wv.w;
                a2 += s2.x * wv.x + s2.y * wv.y + s2.z * wv.z + s2.w * wv.w;
                a3 += s3.x * wv.x + s3.y * wv.y + s3.z * wv.z + s3.w * wv.w;
            }
        }
        a0 += __shfl_xor(a0, 32);           // combine i4 halves
        a1 += __shfl_xor(a1, 32);
        a2 += __shfl_xor(a2, 32);
        a3 += __shfl_xor(a3, 32);
        if (hf == 0) {
            Olds[w][0][o] = a0; Olds[w][1][o] = a1;
            Olds[w][2][o] = a2; Olds[w][3][o] = a3;
        }
    }
    __syncthreads();

    // ---- finalize: 128 threads = 4 nodes x 32 lanes; root+bias already folded
    if (t < 4 * DOUT) {
        int m = t >> 5, o2 = t & 31;
        int n2 = perm[blockIdx.x * 4 + m];
        float d = (float)cnt[n2]; if (d < 1.f) d = 1.f;
        float r = (Olds[0][m][o2] + Olds[1][m][o2] + Olds[2][m][o2] + Olds[3][m][o2]) / d;
        r = r > 0.f ? r : expm1f(r);
        if (FINAL) atomicAdd(gsum + batch[n2] * DOUT + o2, r);
        else xout[n2 * DOUT + o2] = r;
    }
}

// ---- final fc; counts precomputed in k_prep (gcnt)
__global__ void k_fc(const float* __restrict__ gsum, const int* __restrict__ gcnt,
                     const float* __restrict__ wfc, const float* __restrict__ bfc,
                     float* __restrict__ out) {
    int g = threadIdx.x;
    if (g >= GG) return;
    float c = (float)gcnt[g]; if (c < 1.f) c = 1.f;
    float acc = 0.f;
#pragma unroll
    for (int o = 0; o < DOUT; o++) acc += gsum[g * DOUT + o] * wfc[o];
    out[g] = acc / c + bfc[0];
}

extern "C" void kernel_launch(void* const* d_in, const int* in_sizes, int n_in,
                              void* d_out, int out_size, void* d_ws, size_t ws_size,
                              hipStream_t stream) {
    const float* x     = (const float*)d_in[0];
    const float* ea    = (const float*)d_in[1];
    const int*   ei    = (const int*)d_in[2];
    const int*   batch = (const int*)d_in[3];
    const float* w1_0 = (const float*)d_in[4];
    const float* b1_0 = (const float*)d_in[5];
    const float* g_0  = (const float*)d_in[6];
    const float* be_0 = (const float*)d_in[7];
    const float* w2_0 = (const float*)d_in[8];
    const float* b2_0 = (const float*)d_in[9];
    const float* wr_0 = (const float*)d_in[10];
    const float* bc_0 = (const float*)d_in[11];
    const float* w1_1 = (const float*)d_in[12];
    const float* b1_1 = (const float*)d_in[13];
    const float* g_1  = (const float*)d_in[14];
    const float* be_1 = (const float*)d_in[15];
    const float* w2_1 = (const float*)d_in[16];
    const float* b2_1 = (const float*)d_in[17];
    const float* wr_1 = (const float*)d_in[18];
    const float* bc_1 = (const float*)d_in[19];
    const float* wfc  = (const float*)d_in[20];
    const float* bfc  = (const float*)d_in[21];

    float* ws    = (float*)d_ws;
    int*   cur   = (int*)(ws + OFF_CUR);
    float* gsum  = ws + OFF_GSUM;
    int*   gcnt  = (int*)(ws + OFF_GCNT);
    int*   binc  = (int*)(ws + OFF_BINC);
    float* mop   = ws + OFF_MOP;
    float* w1f0  = ws + OFF_W1F0;
    float* b1f0  = ws + OFF_B1F0;
    float* w1f1  = ws + OFF_W1F1;
    float* b1f1  = ws + OFF_B1F1;
    int*   boff  = (int*)(ws + OFF_BOFF);
    int*   perm  = (int*)(ws + OFF_PERM);
    float* eab   = ws + OFF_EA;
    float* wb0   = ws + OFF_WB0;
    float* wb1   = ws + OFF_WB1;
    float* x1    = ws + OFF_X1;

    hipMemsetAsync(ws, 0, (size_t)ZERO_FLOATS * sizeof(float), stream);

    // prep: pack + moment partials (plain stores) + bucket scatter + gcnt
    k_prep<<<PREPB, 256, 0, stream>>>(ea, ei, batch,
                                      w2_0, b2_0, wr_0, bc_0, w2_1, b2_1, wr_1, bc_1,
                                      mop, cur, gcnt, eab, wb0, wb1);
    // reduce partials + BN fold + degree histogram/prefix (1 block)
    k_fold<<<1, 256, 0, stream>>>(mop, cur,
                                  w1_0, b1_0, g_0, be_0, w1_1, b1_1, g_1, be_1,
                                  w1f0, b1f0, w1f1, b1f1, boff);
    // degree-sorted node permutation (counting-sort scatter)
    k_perm<<<(NN + 255) / 256, 256, 0, stream>>>(cur, boff, binc, perm);

    // layer 0 (din=16)
    k_fused<16, 8, false><<<NN / 4, 256, 0, stream>>>(cur, perm, eab, w1f0, b1f0,
                                                      wb0, x, batch, x1, gsum);
    // layer 1 (din=32), pool epilogue fused
    k_fused<32, 16, true><<<NN / 4, 256, 0, stream>>>(cur, perm, eab, w1f1, b1f1,
                                                      wb1, x1, batch, nullptr, gsum);

    // fc
    k_fc<<<1, 128, 0, stream>>>(gsum, gcnt, wfc, bfc, (float*)d_out);
}

// Round 18
// 193.537 us; speedup vs baseline: 1.1763x; 1.1763x over previous
//
#include <hip/hip_runtime.h>
#include <math.h>

// Problem constants (fixed by reference)
#define NN   10000
#define EE   160000
#define GG   128
#define HIDK 25
#define KROWS 32     // 25 MLP rows + 1 b2 row + 1 wr row (26) + 1 bc row (27) + 4 pad
#define KB   28      // Phase-B row count (rows 0..27 are real)
#define DOUT 32
#define EPSBN 1e-5f
#define PREPB 1024   // k_prep grid: 262144 threads -> 1 edge/thread, 4 waves/SIMD
#define WPACKN (KROWS * 16 * DOUT + KROWS * 32 * DOUT)   // 49152
#define MAXD 48      // padded bucket slots/node; Poisson(16): P(>48)~1e-12 -> safe

// ---------------- workspace layout (float offsets) ----------------
// zeroed region (one hipMemsetAsync):
#define OFF_CUR   0          // NN ints (bucket cursors == final degrees), pad 10016
#define OFF_GSUM  10016      // G*32 = 4096
#define OFF_GCNT  14112      // GG ints, pad 128
#define ZERO_FLOATS 14240
// non-zeroed:
#define OFF_MOP   14240      // PREPB*12 per-block moment partials (plain stores)
#define OFF_W1F0  26528      // 80
#define OFF_B1F0  26608      // 32
#define OFF_W1F1  26640      // 80
#define OFF_B1F1  26720      // 32
#define OFF_EA    26752      // NN*MAXD*4 floats: {a0,a1,a2,src-bits} in bucket order
#define OFF_WB0   1946752    // 32*16*32 = 16384
#define OFF_WB1   1963136    // 32*32*32 = 32768
#define OFF_X1    1995904    // N*32
#define TOTAL_FLOATS 2315904 // ~9.3 MB of d_ws

// ============================================================================
// SESSION LEDGER (FINAL, R18 = R12/R15 verbatim -- best verified: 196-198 us
// over 3 clean runs; session start was 277 us). Closed findings:
//  * k_fused: MINW=6 + shallow (1-iter) prefetch ONLY. Any added per-wave
//    state spills to scratch: MINW=7/8 (R3/R6/R13), 3-deep pipeline (R14)
//    -> WRITE_SIZE 29-185 MB, 1.4-2.4x slower. Compiler register-budget wall.
//  * Phase-B remap ("one ds_read serves 4 nodes"): abandoned -- slower with
//    bank conflicts (R10, 2.28M) AND without (R11, codegen regression).
//  * Grid-wide tickets only at O(100) blocks: 192 ok (R7), 1024 convoy (R8),
//    2500 convoy (R5). Same-line atomics across 1000+ blocks serialize (R9)
//    -> per-block partials + 1-block reduce kernel.
//  * Degree-sorted node order (R17): per-dispatch k_fused win (~2-3 us) but
//    graded total regressed (+31 us, cause not isolatable from counters) ->
//    reverted per post-mortem discipline.
//  * Residual state: fused kernels ~47% VALUBusy, 2.5% HBM -- latency-bound
//    at the hipcc spill threshold; not a hardware roofline.
// ============================================================================

__device__ inline float wave_red(float v) {
    for (int off = 32; off; off >>= 1) v += __shfl_down(v, off);
    return v;
}

// ---- pack wbig[k][i4][o][c] = W[k][i4*4+c][o]   (R9-proven layout)
// rows 0..24 = w2; 25 = b2; 26 = wr (root fold); 27 = bc (bias, i==0); rest 0
template <int DIN>
__device__ inline void wpack(int idx, const float* __restrict__ w2,
                             const float* __restrict__ b2,
                             const float* __restrict__ wr,
                             const float* __restrict__ bc,
                             float* __restrict__ wbig) {
    int k = idx / (DIN * DOUT);
    int rem = idx - k * (DIN * DOUT);
    int i4 = rem / (4 * DOUT);
    int rem2 = rem - i4 * (4 * DOUT);
    int o = rem2 >> 2, c = rem2 & 3;
    int i = i4 * 4 + c;
    float v = 0.f;
    if (k < HIDK) v = w2[(k * DIN + i) * DOUT + o];
    else if (k == HIDK) v = b2[i * DOUT + o];
    else if (k == HIDK + 1) v = wr[i * DOUT + o];
    else if (k == HIDK + 2) v = (i == 0) ? bc[o] : 0.f;
    wbig[idx] = v;
}

// ---- prep kernel, 1024 blocks, one edge/thread. NO grid ticket (R8: convoy),
// NO same-line gmom atomics (R9): moments -> per-block partials (plain stores).
__global__ void k_prep(const float* __restrict__ ea, const int* __restrict__ ei,
                       const int* __restrict__ batch,
                       const float* __restrict__ w2_0, const float* __restrict__ b2_0,
                       const float* __restrict__ wr_0, const float* __restrict__ bc_0,
                       const float* __restrict__ w2_1, const float* __restrict__ b2_1,
                       const float* __restrict__ wr_1, const float* __restrict__ bc_1,
                       float* __restrict__ mop, int* __restrict__ cur,
                       int* __restrict__ gcnt, float* __restrict__ eab,
                       float* __restrict__ wb0, float* __restrict__ wb1) {
    __shared__ float ls[4][9];
    int t = threadIdx.x;
    int idx = blockIdx.x * 256 + t;

    // -- weight pack (guarded; independent)
    if (idx < KROWS * 16 * DOUT) wpack<16>(idx, w2_0, b2_0, wr_0, bc_0, wb0);
    else if (idx < WPACKN) wpack<32>(idx - KROWS * 16 * DOUT, w2_1, b2_1, wr_1, bc_1, wb1);

    // -- one edge per thread: moments + bucket scatter (single 16B write;
    //    src index embedded in .w as int bits -> no separate bsrc array)
    float s[9];
#pragma unroll
    for (int j = 0; j < 9; j++) s[j] = 0.f;
    if (idx < EE) {
        float a0 = ea[3 * idx], a1 = ea[3 * idx + 1], a2 = ea[3 * idx + 2];
        s[0] = a0; s[1] = a1; s[2] = a2;
        s[3] = a0 * a0; s[4] = a0 * a1; s[5] = a0 * a2;
        s[6] = a1 * a1; s[7] = a1 * a2; s[8] = a2 * a2;
        int d = ei[EE + idx];
        int pos = atomicAdd(cur + d, 1);
        if (pos < MAXD) {                       // deterministically never exceeded
            int slot = d * MAXD + pos;
            float4 av = { a0, a1, a2, __int_as_float(ei[idx]) };
            *(float4*)(eab + 4 * (size_t)slot) = av;
        }
    }
    // -- nodes-per-graph counts (128 counters, ~80 RMW/line -> fine)
    if (idx < NN) atomicAdd(gcnt + batch[idx], 1);

    int w = t >> 6, lane = t & 63;
#pragma unroll
    for (int j = 0; j < 9; j++) {
        float r = wave_red(s[j]);
        if (lane == 0) ls[w][j] = r;
    }
    __syncthreads();
    if (t < 9) mop[blockIdx.x * 12 + t] = ls[0][t] + ls[1][t] + ls[2][t] + ls[3][t];
}

// ---- reduce moment partials + BN fold, 1 block x 256 threads (stream order
// replaces any device ticket)
__global__ void k_fold(const float* __restrict__ mop,
                       const float* __restrict__ w1_0, const float* __restrict__ b1_0,
                       const float* __restrict__ g_0, const float* __restrict__ be_0,
                       const float* __restrict__ w1_1, const float* __restrict__ b1_1,
                       const float* __restrict__ g_1, const float* __restrict__ be_1,
                       float* __restrict__ w1f0, float* __restrict__ b1f0,
                       float* __restrict__ w1f1, float* __restrict__ b1f1) {
    __shared__ float ls[4][9];
    __shared__ float mo[9];
    int t = threadIdx.x;
    float s[9];
#pragma unroll
    for (int j = 0; j < 9; j++) s[j] = 0.f;
    for (int b = t; b < PREPB; b += 256) {
#pragma unroll
        for (int j = 0; j < 9; j++) s[j] += mop[b * 12 + j];
    }
    int w = t >> 6, lane = t & 63;
#pragma unroll
    for (int j = 0; j < 9; j++) {
        float r = wave_red(s[j]);
        if (lane == 0) ls[w][j] = r;
    }
    __syncthreads();
    if (t < 9) mo[t] = ls[0][t] + ls[1][t] + ls[2][t] + ls[3][t];
    __syncthreads();
    if (t < 64) {
        int grp = t >> 5, j = t & 31;
        if (j < HIDK) {
            const float* w1 = grp ? w1_1 : w1_0;
            const float* b1 = grp ? b1_1 : b1_0;
            const float* g  = grp ? g_1  : g_0;
            const float* be = grp ? be_1 : be_0;
            float* w1f = grp ? w1f1 : w1f0;
            float* b1f = grp ? b1f1 : b1f0;
            const float inv = 1.0f / (float)EE;
            float m0 = mo[0] * inv, m1 = mo[1] * inv, m2 = mo[2] * inv;
            float c00 = mo[3] * inv - m0 * m0, c01 = mo[4] * inv - m0 * m1;
            float c02 = mo[5] * inv - m0 * m2, c11 = mo[6] * inv - m1 * m1;
            float c12 = mo[7] * inv - m1 * m2, c22 = mo[8] * inv - m2 * m2;
            float w0 = w1[j], wa = w1[25 + j], wb = w1[50 + j];
            float mean = m0 * w0 + m1 * wa + m2 * wb + b1[j];
            float var = w0 * w0 * c00 + wa * wa * c11 + wb * wb * c22
                      + 2.f * (w0 * wa * c01 + w0 * wb * c02 + wa * wb * c12);
            float sc = g[j] * rsqrtf(var + EPSBN);
            w1f[j] = w0 * sc; w1f[25 + j] = wa * sc; w1f[50 + j] = wb * sc;
            b1f[j] = (b1[j] - mean) * sc + be[j];
        }
    }
}

// ---- FUSED layer kernel (R12 proven optimum). ONE wave per node, 4 nodes/
// block, start = n*MAXD. MINW=6 + shallow (1-iter) prefetch ONLY -- see ledger.
// Phase A: single load stream -- src rides in eab.w, extracted via 2 broadcast
// shuffles; h lane-parallel, double-buffered through LDS (intra-wave, no
// barrier: same-wave DS ops complete in program order).
// Phase B (R9 v1): wave w covers k-rows [7w,7w+7) for ALL 4 nodes, half-waves
// split the i4 range; W read once per block.
// FINAL=true: epilogue atomicAdds into gsum ONLY (no grid ticket -- R5).
template <int DIN, int KPL, bool FINAL>
__global__ __launch_bounds__(256, 6)
void k_fused(const int* __restrict__ cnt,
             const float* __restrict__ eab,
             const float* __restrict__ w1f, const float* __restrict__ b1f,
             const float* __restrict__ wbig, const float* __restrict__ xin,
             const int* __restrict__ batch,
             float* __restrict__ xout, float* __restrict__ gsum) {
    __shared__ __align__(16) float Slds[4][KROWS][DIN];
    __shared__ float Olds[4][4][DOUT];                 // [wave][node][o]
    __shared__ __align__(16) float hb[4][2][2][32];    // [wave][buf][half][k]
    int t = threadIdx.x;
    int w = t >> 6, lane = t & 63;
    int n = blockIdx.x * 4 + w;            // grid 2500 -> n in [0,10000)
    int dg = cnt[n];
    int start = n * MAXD;
    int end = start + (dg > MAXD ? MAXD : dg);

    int il = lane & (DIN - 1);
    int kh = lane / DIN;                   // 64/DIN k-groups
    int kme = lane & 31;                   // which h-row this lane computes
    int half = lane >> 5;                  // 0: edge A (p), 1: edge B (p+1)

    // per-lane folded edge-MLP coefficients (loop-invariant)
    float c0 = 0.f, c1 = 0.f, c2 = 0.f, c3 = 0.f;
    if (kme < HIDK) {
        c0 = w1f[kme]; c1 = w1f[25 + kme]; c2 = w1f[50 + kme]; c3 = b1f[kme];
    } else if (kme == HIDK) {
        c3 = 1.0f;                         // b2 row: relu(1) == 1
    }

    float x_own = xin[n * DIN + il];       // own-node feature (root-fold row 26)

    float s[KPL];
#pragma unroll
    for (int j = 0; j < KPL; j++) s[j] = 0.f;

    const float4* ea4 = (const float4*)eab;

    // ---- Phase A (software-pipelined, 2 edges/iter) ----
    int p = start;
    int vB0 = 0, vB1 = 0;
    float xA = 0.f, xB = 0.f;              // x values for pair p
    float4 av1 = {0.f, 0.f, 0.f, 0.f};     // attrs+src for pair p+2 (this half)
    int buf = 0;

    if (p < end) {
        vB0 = (p + 1 < end); int qB0 = vB0 ? p + 1 : p;
        float4 av0 = ea4[half ? qB0 : p];
        int p1 = p + 2;
        if (p1 < end) {
            vB1 = (p1 + 1 < end); int qB1 = vB1 ? p1 + 1 : p1;
            av1 = ea4[half ? qB1 : p1];
        }
        int me0 = __float_as_int(av0.w);
        int sA0 = __shfl(me0, 0), sB0 = __shfl(me0, 32);
        xA = xin[sA0 * DIN + il];
        xB = xin[sB0 * DIN + il];
        float hv = av0.x * c0 + av0.y * c1 + av0.z * c2 + c3;
        hv = hv > 0.f ? hv : 0.f;
        hb[w][0][half][kme] = hv;
    }
    while (p < end) {
        int p1 = p + 2, p2 = p + 4;
        // prefetch next-next pair's attrs+src (address-only dependency)
        float4 av2 = {0.f, 0.f, 0.f, 0.f};
        int vB2 = 0;
        if (p2 < end) {
            vB2 = (p2 + 1 < end); int qB2 = vB2 ? p2 + 1 : p2;
            av2 = ea4[half ? qB2 : p2];
        }
        // extract next pair's srcs from av1 (arrived) and prefetch x
        int me1 = __float_as_int(av1.w);
        int sA1 = __shfl(me1, 0), sB1 = __shfl(me1, 32);
        float xAn = 0.f, xBn = 0.f;
        if (p1 < end) { xAn = xin[sA1 * DIN + il]; xBn = xin[sB1 * DIN + il]; }
        // read current h BEFORE this iter's write (in-order DS queue, same wave)
        const float4* hA4 = (const float4*)&hb[w][buf][0][kh * KPL];
        const float4* hB4 = (const float4*)&hb[w][buf][1][kh * KPL];
        float4 ha[KPL / 4], hc[KPL / 4];
#pragma unroll
        for (int j4 = 0; j4 < KPL / 4; j4++) { ha[j4] = hA4[j4]; hc[j4] = hB4[j4]; }
        // write next pair's h (av1 arrived)
        if (p1 < end) {
            float hv = av1.x * c0 + av1.y * c1 + av1.z * c2 + c3;
            hv = hv > 0.f ? hv : 0.f;
            hb[w][buf ^ 1][half][kme] = hv;
        }
        float xBm = vB0 ? xB : 0.f;
#pragma unroll
        for (int j4 = 0; j4 < KPL / 4; j4++) {
            s[j4 * 4 + 0] += ha[j4].x * xA; s[j4 * 4 + 1] += ha[j4].y * xA;
            s[j4 * 4 + 2] += ha[j4].z * xA; s[j4 * 4 + 3] += ha[j4].w * xA;
        }
#pragma unroll
        for (int j4 = 0; j4 < KPL / 4; j4++) {
            s[j4 * 4 + 0] += hc[j4].x * xBm; s[j4 * 4 + 1] += hc[j4].y * xBm;
            s[j4 * 4 + 2] += hc[j4].z * xBm; s[j4 * 4 + 3] += hc[j4].w * xBm;
        }
        p = p1;
        vB0 = vB1; vB1 = vB2;
        xA = xAn; xB = xBn; av1 = av2;
        buf ^= 1;
    }
#pragma unroll
    for (int j = 0; j < KPL; j++)
        Slds[w][kh * KPL + j][il] = s[j];
    // fold rows: 26 = d*x_own (root), 27 = d at i==0 (bias). Same-wave later
    // writes override the zeros Phase A stored there (LDS ops in program order).
    float dmul = (float)dg; if (dmul < 1.f) dmul = 1.f;
    if (half == 0) {
        Slds[w][26][il] = dmul * x_own;
        Slds[w][27][il] = (il == 0) ? dmul : 0.f;
    }
    __syncthreads();

    // ---- Phase B (R9): wave w covers k-rows [7w, 7w+7) for all 4 nodes;
    //      half-waves split the i4 range; each W float4 read once per block.
    {
        int o = lane & 31, hf = lane >> 5;
        constexpr int I4H = DIN / 8;        // i4 per half-wave
        const float4* wb4 = (const float4*)wbig;
        float a0 = 0.f, a1 = 0.f, a2 = 0.f, a3 = 0.f;
        int kbase = w * (KB / 4);
#pragma unroll
        for (int kk = 0; kk < KB / 4; kk++) {
            int k = kbase + kk;
#pragma unroll
            for (int j = 0; j < I4H; j++) {
                int i4 = hf * I4H + j;
                float4 wv = wb4[(k * (DIN / 4) + i4) * 32 + o];
                float4 s0 = *(const float4*)&Slds[0][k][i4 * 4];
                float4 s1 = *(const float4*)&Slds[1][k][i4 * 4];
                float4 s2 = *(const float4*)&Slds[2][k][i4 * 4];
                float4 s3 = *(const float4*)&Slds[3][k][i4 * 4];
                a0 += s0.x * wv.x + s0.y * wv.y + s0.z * wv.z + s0.w * wv.w;
                a1 += s1.x * wv.x + s1.y * wv.y + s1.z * wv.z + s1.w * wv.w;
                a2 += s2.x * wv.x + s2.y * wv.y + s2.z * wv.z + s2.w * wv.w;
                a3 += s3.x * wv.x + s3.y * wv.y + s3.z * wv.z + s3.w * wv.w;
            }
        }
        a0 += __shfl_xor(a0, 32);           // combine i4 halves
        a1 += __shfl_xor(a1, 32);
        a2 += __shfl_xor(a2, 32);
        a3 += __shfl_xor(a3, 32);
        if (hf == 0) {
            Olds[w][0][o] = a0; Olds[w][1][o] = a1;
            Olds[w][2][o] = a2; Olds[w][3][o] = a3;
        }
    }
    __syncthreads();

    // ---- finalize: 128 threads = 4 nodes x 32 lanes; root+bias already folded
    if (t < 4 * DOUT) {
        int m = t >> 5, o2 = t & 31;
        int n2 = blockIdx.x * 4 + m;
        float d = (float)cnt[n2]; if (d < 1.f) d = 1.f;
        float r = (Olds[0][m][o2] + Olds[1][m][o2] + Olds[2][m][o2] + Olds[3][m][o2]) / d;
        r = r > 0.f ? r : expm1f(r);
        if (FINAL) atomicAdd(gsum + batch[n2] * DOUT + o2, r);
        else xout[n2 * DOUT + o2] = r;
    }
}

// ---- final fc; counts precomputed in k_prep (gcnt)
__global__ void k_fc(const float* __restrict__ gsum, const int* __restrict__ gcnt,
                     const float* __restrict__ wfc, const float* __restrict__ bfc,
                     float* __restrict__ out) {
    int g = threadIdx.x;
    if (g >= GG) return;
    float c = (float)gcnt[g]; if (c < 1.f) c = 1.f;
    float acc = 0.f;
#pragma unroll
    for (int o = 0; o < DOUT; o++) acc += gsum[g * DOUT + o] * wfc[o];
    out[g] = acc / c + bfc[0];
}

extern "C" void kernel_launch(void* const* d_in, const int* in_sizes, int n_in,
                              void* d_out, int out_size, void* d_ws, size_t ws_size,
                              hipStream_t stream) {
    const float* x     = (const float*)d_in[0];
    const float* ea    = (const float*)d_in[1];
    const int*   ei    = (const int*)d_in[2];
    const int*   batch = (const int*)d_in[3];
    const float* w1_0 = (const float*)d_in[4];
    const float* b1_0 = (const float*)d_in[5];
    const float* g_0  = (const float*)d_in[6];
    const float* be_0 = (const float*)d_in[7];
    const float* w2_0 = (const float*)d_in[8];
    const float* b2_0 = (const float*)d_in[9];
    const float* wr_0 = (const float*)d_in[10];
    const float* bc_0 = (const float*)d_in[11];
    const float* w1_1 = (const float*)d_in[12];
    const float* b1_1 = (const float*)d_in[13];
    const float* g_1  = (const float*)d_in[14];
    const float* be_1 = (const float*)d_in[15];
    const float* w2_1 = (const float*)d_in[16];
    const float* b2_1 = (const float*)d_in[17];
    const float* wr_1 = (const float*)d_in[18];
    const float* bc_1 = (const float*)d_in[19];
    const float* wfc  = (const float*)d_in[20];
    const float* bfc  = (const float*)d_in[21];

    float* ws    = (float*)d_ws;
    int*   cur   = (int*)(ws + OFF_CUR);
    float* gsum  = ws + OFF_GSUM;
    int*   gcnt  = (int*)(ws + OFF_GCNT);
    float* mop   = ws + OFF_MOP;
    float* w1f0  = ws + OFF_W1F0;
    float* b1f0  = ws + OFF_B1F0;
    float* w1f1  = ws + OFF_W1F1;
    float* b1f1  = ws + OFF_B1F1;
    float* eab   = ws + OFF_EA;
    float* wb0   = ws + OFF_WB0;
    float* wb1   = ws + OFF_WB1;
    float* x1    = ws + OFF_X1;

    hipMemsetAsync(ws, 0, (size_t)ZERO_FLOATS * sizeof(float), stream);

    // prep: pack + moment partials (plain stores) + bucket scatter + gcnt
    k_prep<<<PREPB, 256, 0, stream>>>(ea, ei, batch,
                                      w2_0, b2_0, wr_0, bc_0, w2_1, b2_1, wr_1, bc_1,
                                      mop, cur, gcnt, eab, wb0, wb1);
    // reduce partials + BN fold (1 block)
    k_fold<<<1, 256, 0, stream>>>(mop, w1_0, b1_0, g_0, be_0, w1_1, b1_1, g_1, be_1,
                                  w1f0, b1f0, w1f1, b1f1);

    // layer 0 (din=16)
    k_fused<16, 8, false><<<NN / 4, 256, 0, stream>>>(cur, eab, w1f0, b1f0,
                                                      wb0, x, batch, x1, gsum);
    // layer 1 (din=32), pool epilogue fused
    k_fused<32, 16, true><<<NN / 4, 256, 0, stream>>>(cur, eab, w1f1, b1f1,
                                                      wb1, x1, batch, nullptr, gsum);

    // fc
    k_fc<<<1, 128, 0, stream>>>(gsum, gcnt, wfc, bfc, (float*)d_out);
}